// Round 11
// baseline (297.169 us; speedup 1.0000x reference)
//
#include <hip/hip_runtime.h>

#define T_DIM 4096
#define B_DIM 256
#define NSEG 4
#define SEGLEN 64
// N_OBS=64, H=8, N_ACT=18

// ws layout: x2t     32 MiB @ 0        float, [tb][b][ti][8]
//            dones_t  4 MiB @ 32 MiB   int,   [tb][b][ti]
//            carryH   1 MiB @ 36 MiB   float, [s][t][8]
//            carryC   1 MiB @ 37 MiB
//            fdbuf  128 KiB @ 38 MiB   int,   [s][t]

// ---------------------------------------------------------------------------
// Kernel A: fused MLP  states(B,T,64) -> x2t transposed; stages dones_t.
// Verified R7/R10 (LDS-staged coalesced reads).
// ---------------------------------------------------------------------------
__global__ __launch_bounds__(256) void mlp_kernel(
    const float* __restrict__ states,
    const int* __restrict__ dones,
    const float* __restrict__ W1, const float* __restrict__ b1,
    const float* __restrict__ W2, const float* __restrict__ b2,
    float* __restrict__ x2t, int* __restrict__ dones_t)
{
    __shared__ float4 w1s4[4][16];
    __shared__ float  w2s[8][4];
    __shared__ float  b1s[4];
    __shared__ float  b2s[8];
    __shared__ float4 stage[4][16 * 17];

    int tid = threadIdx.x;
    ((float*)w1s4)[tid] = W1[tid];
    if (tid < 32) ((float*)w2s)[tid] = W2[tid];
    if (tid < 4)  b1s[tid] = b1[tid];
    if (tid >= 8 && tid < 16) b2s[tid - 8] = b2[tid - 8];

    if (tid < 64) {
        int r2 = blockIdx.x * 64 + tid;
        int b = r2 >> 12, t = r2 & 4095;
        dones_t[(size_t)(t >> 3) * (B_DIM * 8) + b * 8 + (t & 7)] = dones[r2];
    }

    int w = tid >> 6;
    int l = tid & 63;

    const float4* src4 = (const float4*)states;
    size_t base_f4 = ((size_t)blockIdx.x * 64 + (size_t)w * 16) * 16;
#pragma unroll
    for (int k = 0; k < 4; ++k) {
        int idx = k * 64 + l;
        int row = idx >> 4, m = idx & 15;
        stage[w][row * 17 + m] = src4[base_f4 + idx];
    }
    __syncthreads();

    int rl = l >> 2;
    int q  = l & 3;
    const float4* rowp = &stage[w][rl * 17];

    float a0 = 0.f, a1 = 0.f, a2 = 0.f, a3 = 0.f;
#pragma unroll
    for (int kk = 0; kk < 4; ++kk) {
        float4 v = rowp[q * 4 + kk];
        float4 w0 = w1s4[0][q * 4 + kk];
        float4 w1v = w1s4[1][q * 4 + kk];
        float4 w2v = w1s4[2][q * 4 + kk];
        float4 w3v = w1s4[3][q * 4 + kk];
        a0 = fmaf(v.x, w0.x, a0); a0 = fmaf(v.y, w0.y, a0);
        a0 = fmaf(v.z, w0.z, a0); a0 = fmaf(v.w, w0.w, a0);
        a1 = fmaf(v.x, w1v.x, a1); a1 = fmaf(v.y, w1v.y, a1);
        a1 = fmaf(v.z, w1v.z, a1); a1 = fmaf(v.w, w1v.w, a1);
        a2 = fmaf(v.x, w2v.x, a2); a2 = fmaf(v.y, w2v.y, a2);
        a2 = fmaf(v.z, w2v.z, a2); a2 = fmaf(v.w, w2v.w, a2);
        a3 = fmaf(v.x, w3v.x, a3); a3 = fmaf(v.y, w3v.y, a3);
        a3 = fmaf(v.z, w3v.z, a3); a3 = fmaf(v.w, w3v.w, a3);
    }
    a0 += __shfl_xor(a0, 1, 64); a1 += __shfl_xor(a1, 1, 64);
    a2 += __shfl_xor(a2, 1, 64); a3 += __shfl_xor(a3, 1, 64);
    a0 += __shfl_xor(a0, 2, 64); a1 += __shfl_xor(a1, 2, 64);
    a2 += __shfl_xor(a2, 2, 64); a3 += __shfl_xor(a3, 2, 64);

    a0 = fmaxf(a0 + b1s[0], 0.f);
    a1 = fmaxf(a1 + b1s[1], 0.f);
    a2 = fmaxf(a2 + b1s[2], 0.f);
    a3 = fmaxf(a3 + b1s[3], 0.f);

    int h0 = 2 * q, h1 = 2 * q + 1;
    float s0 = b2s[h0];
    s0 = fmaf(a0, w2s[h0][0], s0); s0 = fmaf(a1, w2s[h0][1], s0);
    s0 = fmaf(a2, w2s[h0][2], s0); s0 = fmaf(a3, w2s[h0][3], s0);
    float s1 = b2s[h1];
    s1 = fmaf(a0, w2s[h1][0], s1); s1 = fmaf(a1, w2s[h1][1], s1);
    s1 = fmaf(a2, w2s[h1][2], s1); s1 = fmaf(a3, w2s[h1][3], s1);
    s0 = fmaxf(s0, 0.f);
    s1 = fmaxf(s1, 0.f);

    int r = blockIdx.x * 64 + w * 16 + rl;
    int b = r >> 12, t = r & 4095;
    size_t f2i = (size_t)(t >> 3) * 8192 + (size_t)b * 32 + (t & 7) * 4 + q;
    ((float2*)x2t)[f2i] = make_float2(s0, s1);
}

// ---------------------------------------------------------------------------
// Shared LSTM pieces (x read directly from x2t).
// ---------------------------------------------------------------------------
#define LOAD_LSTM_WEIGHTS                                                      \
    float wI[8], wF[8], wG[8], wO[8], uI[8], uF[8], uG[8], uO[8];              \
    _Pragma("unroll") for (int k = 0; k < 8; ++k) {                            \
        wI[k] = Wih[j * 8 + k];        uI[k] = Whh[j * 8 + k];                 \
        wF[k] = Wih[(8 + j) * 8 + k];  uF[k] = Whh[(8 + j) * 8 + k];           \
        wG[k] = Wih[(16 + j) * 8 + k]; uG[k] = Whh[(16 + j) * 8 + k];          \
        wO[k] = Wih[(24 + j) * 8 + k]; uO[k] = Whh[(24 + j) * 8 + k];          \
    }                                                                          \
    float bI = bih[j] + bhh[j],      bF = bih[8 + j] + bhh[8 + j];             \
    float bG = bih[16 + j] + bhh[16 + j], bO = bih[24 + j] + bhh[24 + j];      \
    float hw0[8], hw1[8], hw2[8];                                              \
    float hb0 = ba[j], hb1 = ba[8 + j], hb2 = 0.f;                             \
    _Pragma("unroll") for (int k = 0; k < 8; ++k) {                            \
        hw0[k] = Wa[j * 8 + k]; hw1[k] = Wa[(8 + j) * 8 + k]; hw2[k] = 0.f;    \
    }                                                                          \
    if (j < 2) {                                                               \
        _Pragma("unroll") for (int k = 0; k < 8; ++k) hw2[k] = Wa[(16+j)*8+k]; \
        hb2 = ba[16 + j];                                                      \
    } else if (j == 2) {                                                       \
        _Pragma("unroll") for (int k = 0; k < 8; ++k) hw2[k] = Wv[k];          \
        hb2 = bv[0];                                                           \
    }

#define CORE_X(DONEE, XA, XB)                                                  \
        float gi = bI, gf = bF, gg = bG, go = bO;                              \
        gi = fmaf(XA.x, wI[0], gi); gi = fmaf(XA.y, wI[1], gi);                \
        gi = fmaf(XA.z, wI[2], gi); gi = fmaf(XA.w, wI[3], gi);                \
        gi = fmaf(XB.x, wI[4], gi); gi = fmaf(XB.y, wI[5], gi);                \
        gi = fmaf(XB.z, wI[6], gi); gi = fmaf(XB.w, wI[7], gi);                \
        gf = fmaf(XA.x, wF[0], gf); gf = fmaf(XA.y, wF[1], gf);                \
        gf = fmaf(XA.z, wF[2], gf); gf = fmaf(XA.w, wF[3], gf);                \
        gf = fmaf(XB.x, wF[4], gf); gf = fmaf(XB.y, wF[5], gf);                \
        gf = fmaf(XB.z, wF[6], gf); gf = fmaf(XB.w, wF[7], gf);                \
        gg = fmaf(XA.x, wG[0], gg); gg = fmaf(XA.y, wG[1], gg);                \
        gg = fmaf(XA.z, wG[2], gg); gg = fmaf(XA.w, wG[3], gg);                \
        gg = fmaf(XB.x, wG[4], gg); gg = fmaf(XB.y, wG[5], gg);                \
        gg = fmaf(XB.z, wG[6], gg); gg = fmaf(XB.w, wG[7], gg);                \
        go = fmaf(XA.x, wO[0], go); go = fmaf(XA.y, wO[1], go);                \
        go = fmaf(XA.z, wO[2], go); go = fmaf(XA.w, wO[3], go);                \
        go = fmaf(XB.x, wO[4], go); go = fmaf(XB.y, wO[5], go);                \
        go = fmaf(XB.z, wO[6], go); go = fmaf(XB.w, wO[7], go);                \
        float dI = h[0] * uI[0], dF = h[0] * uF[0];                            \
        float dG = h[0] * uG[0], dO = h[0] * uO[0];                            \
        dI = fmaf(h[1], uI[1], dI); dF = fmaf(h[1], uF[1], dF);                \
        dG = fmaf(h[1], uG[1], dG); dO = fmaf(h[1], uO[1], dO);                \
        dI = fmaf(h[2], uI[2], dI); dF = fmaf(h[2], uF[2], dF);                \
        dG = fmaf(h[2], uG[2], dG); dO = fmaf(h[2], uO[2], dO);                \
        dI = fmaf(h[3], uI[3], dI); dF = fmaf(h[3], uF[3], dF);                \
        dG = fmaf(h[3], uG[3], dG); dO = fmaf(h[3], uO[3], dO);                \
        dI = fmaf(h[4], uI[4], dI); dF = fmaf(h[4], uF[4], dF);                \
        dG = fmaf(h[4], uG[4], dG); dO = fmaf(h[4], uO[4], dO);                \
        dI = fmaf(h[5], uI[5], dI); dF = fmaf(h[5], uF[5], dF);                \
        dG = fmaf(h[5], uG[5], dG); dO = fmaf(h[5], uO[5], dO);                \
        dI = fmaf(h[6], uI[6], dI); dF = fmaf(h[6], uF[6], dF);                \
        dG = fmaf(h[6], uG[6], dG); dO = fmaf(h[6], uO[6], dO);                \
        dI = fmaf(h[7], uI[7], dI); dF = fmaf(h[7], uF[7], dF);                \
        dG = fmaf(h[7], uG[7], dG); dO = fmaf(h[7], uO[7], dO);                \
        float GI = (DONEE) ? gi : (gi + dI);                                   \
        float GF = (DONEE) ? gf : (gf + dF);                                   \
        float GG = (DONEE) ? gg : (gg + dG);                                   \
        float GO = (DONEE) ? go : (go + dO);                                   \
        float cin = (DONEE) ? 0.f : c;                                         \
        float i_ = 1.f / (1.f + __expf(-GI));                                  \
        float f_ = 1.f / (1.f + __expf(-GF));                                  \
        float g_ = 2.f / (1.f + __expf(-2.f * GG)) - 1.f;                      \
        float o_ = 1.f / (1.f + __expf(-GO));                                  \
        float c2 = fmaf(f_, cin, i_ * g_);                                     \
        float th = 2.f / (1.f + __expf(-2.f * c2)) - 1.f;                      \
        float h2 = o_ * th;

#define HEADS                                                                  \
        float o0 = hb0, o1 = hb1, o2 = hb2;                                    \
        o0 = fmaf(h[0], hw0[0], o0); o1 = fmaf(h[0], hw1[0], o1);              \
        o2 = fmaf(h[0], hw2[0], o2);                                           \
        o0 = fmaf(h[1], hw0[1], o0); o1 = fmaf(h[1], hw1[1], o1);              \
        o2 = fmaf(h[1], hw2[1], o2);                                           \
        o0 = fmaf(h[2], hw0[2], o0); o1 = fmaf(h[2], hw1[2], o1);              \
        o2 = fmaf(h[2], hw2[2], o2);                                           \
        o0 = fmaf(h[3], hw0[3], o0); o1 = fmaf(h[3], hw1[3], o1);              \
        o2 = fmaf(h[3], hw2[3], o2);                                           \
        o0 = fmaf(h[4], hw0[4], o0); o1 = fmaf(h[4], hw1[4], o1);              \
        o2 = fmaf(h[4], hw2[4], o2);                                           \
        o0 = fmaf(h[5], hw0[5], o0); o1 = fmaf(h[5], hw1[5], o1);              \
        o2 = fmaf(h[5], hw2[5], o2);                                           \
        o0 = fmaf(h[6], hw0[6], o0); o1 = fmaf(h[6], hw1[6], o1);              \
        o2 = fmaf(h[6], hw2[6], o2);                                           \
        o0 = fmaf(h[7], hw0[7], o0); o1 = fmaf(h[7], hw1[7], o1);              \
        o2 = fmaf(h[7], hw2[7], o2);

// ---------------------------------------------------------------------------
// Pass 1: segmented scan over x2t. Block = 1 wave = (segment s, 8 t-columns).
// NSEG=4 -> 2048 waves, all co-resident. VGPR diet: 1-deep prefetch (x2t and
// dones_t are L3-resident after mlp_kernel), launch_bounds(64,4) caps VGPR
// at 128 -> 4 waves/SIMD capacity (stall hiding doubles vs R10).
// ---------------------------------------------------------------------------
__global__ __launch_bounds__(64, 4) void pass1_kernel(
    const float* __restrict__ x2t, const int* __restrict__ dones_t,
    const float* __restrict__ hx,
    const float* __restrict__ Wih, const float* __restrict__ bih,
    const float* __restrict__ Whh, const float* __restrict__ bhh,
    const float* __restrict__ Wa, const float* __restrict__ ba,
    const float* __restrict__ Wv, const float* __restrict__ bv,
    float* __restrict__ out,
    float* __restrict__ carryH, float* __restrict__ carryC,
    int* __restrict__ fdbuf)
{
    int lane = threadIdx.x;
    int col  = lane >> 3;
    int j    = lane & 7;
    int gb   = lane & 56;
    int s    = blockIdx.x >> 9;
    int tb   = blockIdx.x & 511;
    int t    = tb * 8 + col;
    int b0   = s * SEGLEN;

    LOAD_LSTM_WEIGHTS

    float h[8]; float c;
    if (s == 0) {
#pragma unroll
        for (int m = 0; m < 8; ++m) h[m] = hx[t * 8 + m];
        c = hx[T_DIM * 8 + t * 8 + j];
    } else {
#pragma unroll
        for (int m = 0; m < 8; ++m) h[m] = 0.f;
        c = 0.f;
    }

    const float4* xt4 = (const float4*)x2t + (size_t)tb * 4096 + col * 2;
    const int*    dtp = dones_t + (size_t)tb * (B_DIM * 8) + col;
    float* outA = out + ((size_t)b0 * T_DIM + t) * 18;
    float* outV = out + (size_t)18 * B_DIM * T_DIM + (size_t)b0 * T_DIM + t;
    int fd = SEGLEN;

    // 1-deep prefetch (L3-resident streams)
    int dn = dtp[(size_t)b0 * 8];
    float4 xa = xt4[(size_t)b0 * 16];
    float4 xv = xt4[(size_t)b0 * 16 + 1];

#pragma unroll 4
    for (int k = 0; k < SEGLEN; ++k) {
        int done = dn; float4 a = xa, v = xv;
        int kp = k + 1; kp = (kp > SEGLEN - 1) ? (SEGLEN - 1) : kp;
        dn = dtp[(size_t)(b0 + kp) * 8];
        xa = xt4[(size_t)(b0 + kp) * 16];
        xv = xt4[(size_t)(b0 + kp) * 16 + 1];
        CORE_X(done, a, v)
        c = c2;
        h[0] = __shfl(h2, gb | 0, 64); h[1] = __shfl(h2, gb | 1, 64);
        h[2] = __shfl(h2, gb | 2, 64); h[3] = __shfl(h2, gb | 3, 64);
        h[4] = __shfl(h2, gb | 4, 64); h[5] = __shfl(h2, gb | 5, 64);
        h[6] = __shfl(h2, gb | 6, 64); h[7] = __shfl(h2, gb | 7, 64);
        fd = (done && fd == SEGLEN) ? k : fd;
        HEADS
        outA[j] = o0; outA[8 + j] = o1;
        if (j < 2) outA[16 + j] = o2; else if (j == 2) *outV = o2;
        outA += (size_t)T_DIM * 18; outV += T_DIM;
    }

    carryH[((size_t)s * T_DIM + t) * 8 + j] = h[j];
    carryC[((size_t)s * T_DIM + t) * 8 + j] = c;
    if (j == 0) fdbuf[(size_t)s * T_DIM + t] = fd;
}

// ---------------------------------------------------------------------------
// Pass 2: serial over segments 1..3; recompute steps [0, fd) with the true
// carry (dones are 0 there by definition of fd), then adopt pass-1's carry.
// ---------------------------------------------------------------------------
__global__ __launch_bounds__(64) void pass2_kernel(
    const float* __restrict__ x2t,
    const float* __restrict__ Wih, const float* __restrict__ bih,
    const float* __restrict__ Whh, const float* __restrict__ bhh,
    const float* __restrict__ Wa, const float* __restrict__ ba,
    const float* __restrict__ Wv, const float* __restrict__ bv,
    float* __restrict__ out,
    const float* __restrict__ carryH, const float* __restrict__ carryC,
    const int* __restrict__ fdbuf)
{
    int lane = threadIdx.x;
    int col  = lane >> 3;
    int j    = lane & 7;
    int gb   = lane & 56;
    int tb   = blockIdx.x;
    int t    = tb * 8 + col;

    LOAD_LSTM_WEIGHTS

    float h[8]; float c;
#pragma unroll
    for (int m = 0; m < 8; ++m) h[m] = carryH[(size_t)t * 8 + m];
    c = carryC[(size_t)t * 8 + j];

    const float4* xt4 = (const float4*)x2t + (size_t)tb * 4096 + col * 2;

    for (int s = 1; s < NSEG; ++s) {
        int fd = fdbuf[(size_t)s * T_DIM + t];
        int wmax = fd;
#pragma unroll
        for (int d = 1; d < 64; d <<= 1) {
            int o = __shfl_xor(wmax, d, 64);
            wmax = (o > wmax) ? o : wmax;
        }
        size_t bbase = (size_t)s * SEGLEN;

        float4 cxa = xt4[bbase * 16], cxv = xt4[bbase * 16 + 1];
        for (int k = 0; k < wmax; ++k) {
            bool act = (k < fd);
            float4 xa = cxa, xv = cxv;
            int kn = k + 1; kn = (kn > SEGLEN - 1) ? (SEGLEN - 1) : kn;
            cxa = xt4[(bbase + kn) * 16];
            cxv = xt4[(bbase + kn) * 16 + 1];
            CORE_X(0, xa, xv)
            c = act ? c2 : c;
            float n0 = __shfl(h2, gb | 0, 64), n1 = __shfl(h2, gb | 1, 64);
            float n2 = __shfl(h2, gb | 2, 64), n3 = __shfl(h2, gb | 3, 64);
            float n4 = __shfl(h2, gb | 4, 64), n5 = __shfl(h2, gb | 5, 64);
            float n6 = __shfl(h2, gb | 6, 64), n7 = __shfl(h2, gb | 7, 64);
            h[0] = act ? n0 : h[0]; h[1] = act ? n1 : h[1];
            h[2] = act ? n2 : h[2]; h[3] = act ? n3 : h[3];
            h[4] = act ? n4 : h[4]; h[5] = act ? n5 : h[5];
            h[6] = act ? n6 : h[6]; h[7] = act ? n7 : h[7];
            HEADS
            if (act) {
                float* outA = out + ((bbase + k) * T_DIM + t) * 18;
                outA[j] = o0; outA[8 + j] = o1;
                if (j < 2) outA[16 + j] = o2;
                else if (j == 2)
                    out[(size_t)18 * B_DIM * T_DIM + (bbase + k) * T_DIM + t] = o2;
            }
        }
        if (fd < SEGLEN) {
#pragma unroll
            for (int m = 0; m < 8; ++m)
                h[m] = carryH[((size_t)s * T_DIM + t) * 8 + m];
            c = carryC[((size_t)s * T_DIM + t) * 8 + j];
        }
    }
}

// ---------------------------------------------------------------------------
extern "C" void kernel_launch(void* const* d_in, const int* in_sizes, int n_in,
                              void* d_out, int out_size, void* d_ws, size_t ws_size,
                              hipStream_t stream) {
    (void)in_sizes; (void)n_in; (void)out_size; (void)ws_size;
    const float* states = (const float*)d_in[0];
    const int*   dones  = (const int*)d_in[1];
    const float* hx     = (const float*)d_in[2];
    const float* W1     = (const float*)d_in[3];
    const float* b1     = (const float*)d_in[4];
    const float* W2     = (const float*)d_in[5];
    const float* b2     = (const float*)d_in[6];
    const float* Wih    = (const float*)d_in[7];
    const float* bih    = (const float*)d_in[8];
    const float* Whh    = (const float*)d_in[9];
    const float* bhh    = (const float*)d_in[10];
    const float* Wa     = (const float*)d_in[11];
    const float* ba     = (const float*)d_in[12];
    const float* Wv     = (const float*)d_in[13];
    const float* bv     = (const float*)d_in[14];
    float* out = (float*)d_out;

    float* x2t     = (float*)d_ws;                               // 32 MiB
    int*   dones_t = (int*)((char*)d_ws + (32u << 20));          // 4 MiB
    float* carryH  = (float*)((char*)d_ws + (36u << 20));        // 1 MiB
    float* carryC  = (float*)((char*)d_ws + (37u << 20));        // 1 MiB
    int*   fdbuf   = (int*)((char*)d_ws + (38u << 20));          // 128 KiB

    mlp_kernel<<<(B_DIM * T_DIM) / 64, 256, 0, stream>>>(states, dones, W1, b1, W2, b2,
                                                         x2t, dones_t);
    pass1_kernel<<<NSEG * 512, 64, 0, stream>>>(x2t, dones_t, hx,
                                                Wih, bih, Whh, bhh, Wa, ba, Wv, bv,
                                                out, carryH, carryC, fdbuf);
    pass2_kernel<<<512, 64, 0, stream>>>(x2t, Wih, bih, Whh, bhh, Wa, ba, Wv, bv,
                                         out, carryH, carryC, fdbuf);
}

// Round 12
// 151.391 us; speedup vs baseline: 1.9629x; 1.9629x over previous
//
#include <hip/hip_runtime.h>

#define T_DIM 4096
#define B_DIM 256
#define NSEG 8
#define SEGLEN 32
// N_OBS=64, H=8, N_ACT=18

// ws layout: x2t     32 MiB @ 0        float, [tb][b][ti][8]
//            dones_t  4 MiB @ 32 MiB   int,   [tb][b][ti]
//            carryH   1 MiB @ 36 MiB   float, [s][t][8]
//            carryC   1 MiB @ 37 MiB
//            fdbuf  128 KiB @ 38 MiB   int,   [s][t]

// ---------------------------------------------------------------------------
// Kernel A: fused MLP  states(B,T,64) -> x2t transposed; stages dones_t.
// Verified R7/R10; ~50 us = its traffic floor (304 MB @ ~6.1 TB/s). Done.
// ---------------------------------------------------------------------------
__global__ __launch_bounds__(256) void mlp_kernel(
    const float* __restrict__ states,
    const int* __restrict__ dones,
    const float* __restrict__ W1, const float* __restrict__ b1,
    const float* __restrict__ W2, const float* __restrict__ b2,
    float* __restrict__ x2t, int* __restrict__ dones_t)
{
    __shared__ float4 w1s4[4][16];
    __shared__ float  w2s[8][4];
    __shared__ float  b1s[4];
    __shared__ float  b2s[8];
    __shared__ float4 stage[4][16 * 17];

    int tid = threadIdx.x;
    ((float*)w1s4)[tid] = W1[tid];
    if (tid < 32) ((float*)w2s)[tid] = W2[tid];
    if (tid < 4)  b1s[tid] = b1[tid];
    if (tid >= 8 && tid < 16) b2s[tid - 8] = b2[tid - 8];

    if (tid < 64) {
        int r2 = blockIdx.x * 64 + tid;
        int b = r2 >> 12, t = r2 & 4095;
        dones_t[(size_t)(t >> 3) * (B_DIM * 8) + b * 8 + (t & 7)] = dones[r2];
    }

    int w = tid >> 6;
    int l = tid & 63;

    const float4* src4 = (const float4*)states;
    size_t base_f4 = ((size_t)blockIdx.x * 64 + (size_t)w * 16) * 16;
#pragma unroll
    for (int k = 0; k < 4; ++k) {
        int idx = k * 64 + l;
        int row = idx >> 4, m = idx & 15;
        stage[w][row * 17 + m] = src4[base_f4 + idx];
    }
    __syncthreads();

    int rl = l >> 2;
    int q  = l & 3;
    const float4* rowp = &stage[w][rl * 17];

    float a0 = 0.f, a1 = 0.f, a2 = 0.f, a3 = 0.f;
#pragma unroll
    for (int kk = 0; kk < 4; ++kk) {
        float4 v = rowp[q * 4 + kk];
        float4 w0 = w1s4[0][q * 4 + kk];
        float4 w1v = w1s4[1][q * 4 + kk];
        float4 w2v = w1s4[2][q * 4 + kk];
        float4 w3v = w1s4[3][q * 4 + kk];
        a0 = fmaf(v.x, w0.x, a0); a0 = fmaf(v.y, w0.y, a0);
        a0 = fmaf(v.z, w0.z, a0); a0 = fmaf(v.w, w0.w, a0);
        a1 = fmaf(v.x, w1v.x, a1); a1 = fmaf(v.y, w1v.y, a1);
        a1 = fmaf(v.z, w1v.z, a1); a1 = fmaf(v.w, w1v.w, a1);
        a2 = fmaf(v.x, w2v.x, a2); a2 = fmaf(v.y, w2v.y, a2);
        a2 = fmaf(v.z, w2v.z, a2); a2 = fmaf(v.w, w2v.w, a2);
        a3 = fmaf(v.x, w3v.x, a3); a3 = fmaf(v.y, w3v.y, a3);
        a3 = fmaf(v.z, w3v.z, a3); a3 = fmaf(v.w, w3v.w, a3);
    }
    a0 += __shfl_xor(a0, 1, 64); a1 += __shfl_xor(a1, 1, 64);
    a2 += __shfl_xor(a2, 1, 64); a3 += __shfl_xor(a3, 1, 64);
    a0 += __shfl_xor(a0, 2, 64); a1 += __shfl_xor(a1, 2, 64);
    a2 += __shfl_xor(a2, 2, 64); a3 += __shfl_xor(a3, 2, 64);

    a0 = fmaxf(a0 + b1s[0], 0.f);
    a1 = fmaxf(a1 + b1s[1], 0.f);
    a2 = fmaxf(a2 + b1s[2], 0.f);
    a3 = fmaxf(a3 + b1s[3], 0.f);

    int h0 = 2 * q, h1 = 2 * q + 1;
    float s0 = b2s[h0];
    s0 = fmaf(a0, w2s[h0][0], s0); s0 = fmaf(a1, w2s[h0][1], s0);
    s0 = fmaf(a2, w2s[h0][2], s0); s0 = fmaf(a3, w2s[h0][3], s0);
    float s1 = b2s[h1];
    s1 = fmaf(a0, w2s[h1][0], s1); s1 = fmaf(a1, w2s[h1][1], s1);
    s1 = fmaf(a2, w2s[h1][2], s1); s1 = fmaf(a3, w2s[h1][3], s1);
    s0 = fmaxf(s0, 0.f);
    s1 = fmaxf(s1, 0.f);

    int r = blockIdx.x * 64 + w * 16 + rl;
    int b = r >> 12, t = r & 4095;
    size_t f2i = (size_t)(t >> 3) * 8192 + (size_t)b * 32 + (t & 7) * 4 + q;
    ((float2*)x2t)[f2i] = make_float2(s0, s1);
}

// ---------------------------------------------------------------------------
// Shared LSTM pieces.
// ---------------------------------------------------------------------------
#define LOAD_LSTM_WEIGHTS                                                      \
    float wI[8], wF[8], wG[8], wO[8], uI[8], uF[8], uG[8], uO[8];              \
    _Pragma("unroll") for (int k = 0; k < 8; ++k) {                            \
        wI[k] = Wih[j * 8 + k];        uI[k] = Whh[j * 8 + k];                 \
        wF[k] = Wih[(8 + j) * 8 + k];  uF[k] = Whh[(8 + j) * 8 + k];           \
        wG[k] = Wih[(16 + j) * 8 + k]; uG[k] = Whh[(16 + j) * 8 + k];          \
        wO[k] = Wih[(24 + j) * 8 + k]; uO[k] = Whh[(24 + j) * 8 + k];          \
    }                                                                          \
    float bI = bih[j] + bhh[j],      bF = bih[8 + j] + bhh[8 + j];             \
    float bG = bih[16 + j] + bhh[16 + j], bO = bih[24 + j] + bhh[24 + j];      \
    float hw0[8], hw1[8], hw2[8];                                              \
    float hb0 = ba[j], hb1 = ba[8 + j], hb2 = 0.f;                             \
    _Pragma("unroll") for (int k = 0; k < 8; ++k) {                            \
        hw0[k] = Wa[j * 8 + k]; hw1[k] = Wa[(8 + j) * 8 + k]; hw2[k] = 0.f;    \
    }                                                                          \
    if (j < 2) {                                                               \
        _Pragma("unroll") for (int k = 0; k < 8; ++k) hw2[k] = Wa[(16+j)*8+k]; \
        hb2 = ba[16 + j];                                                      \
    } else if (j == 2) {                                                       \
        _Pragma("unroll") for (int k = 0; k < 8; ++k) hw2[k] = Wv[k];          \
        hb2 = bv[0];                                                           \
    }

// One LSTM step on chain state (H, C, FD) with streams (DN, XA, XV via ptrs).
// Emits outputs and advances OUTA/OUTV. K = step index within segment.
#define P1STEP(K, H, C, FD, DN, XA, XV, DTP, XT4, OUTA, OUTV)                  \
    {                                                                          \
        int done = DN; float4 a = XA, v = XV;                                  \
        int kp = (K) + 1; kp = (kp > SEGLEN - 1) ? (SEGLEN - 1) : kp;          \
        DN = DTP[(size_t)(b0 + kp) * 8];                                       \
        XA = XT4[(size_t)(b0 + kp) * 16];                                      \
        XV = XT4[(size_t)(b0 + kp) * 16 + 1];                                  \
        float gi = bI, gf = bF, gg = bG, go = bO;                              \
        gi = fmaf(a.x, wI[0], gi); gi = fmaf(a.y, wI[1], gi);                  \
        gi = fmaf(a.z, wI[2], gi); gi = fmaf(a.w, wI[3], gi);                  \
        gi = fmaf(v.x, wI[4], gi); gi = fmaf(v.y, wI[5], gi);                  \
        gi = fmaf(v.z, wI[6], gi); gi = fmaf(v.w, wI[7], gi);                  \
        gf = fmaf(a.x, wF[0], gf); gf = fmaf(a.y, wF[1], gf);                  \
        gf = fmaf(a.z, wF[2], gf); gf = fmaf(a.w, wF[3], gf);                  \
        gf = fmaf(v.x, wF[4], gf); gf = fmaf(v.y, wF[5], gf);                  \
        gf = fmaf(v.z, wF[6], gf); gf = fmaf(v.w, wF[7], gf);                  \
        gg = fmaf(a.x, wG[0], gg); gg = fmaf(a.y, wG[1], gg);                  \
        gg = fmaf(a.z, wG[2], gg); gg = fmaf(a.w, wG[3], gg);                  \
        gg = fmaf(v.x, wG[4], gg); gg = fmaf(v.y, wG[5], gg);                  \
        gg = fmaf(v.z, wG[6], gg); gg = fmaf(v.w, wG[7], gg);                  \
        go = fmaf(a.x, wO[0], go); go = fmaf(a.y, wO[1], go);                  \
        go = fmaf(a.z, wO[2], go); go = fmaf(a.w, wO[3], go);                  \
        go = fmaf(v.x, wO[4], go); go = fmaf(v.y, wO[5], go);                  \
        go = fmaf(v.z, wO[6], go); go = fmaf(v.w, wO[7], go);                  \
        float dI = H[0] * uI[0], dF = H[0] * uF[0];                            \
        float dG = H[0] * uG[0], dO = H[0] * uO[0];                            \
        dI = fmaf(H[1], uI[1], dI); dF = fmaf(H[1], uF[1], dF);                \
        dG = fmaf(H[1], uG[1], dG); dO = fmaf(H[1], uO[1], dO);                \
        dI = fmaf(H[2], uI[2], dI); dF = fmaf(H[2], uF[2], dF);                \
        dG = fmaf(H[2], uG[2], dG); dO = fmaf(H[2], uO[2], dO);                \
        dI = fmaf(H[3], uI[3], dI); dF = fmaf(H[3], uF[3], dF);                \
        dG = fmaf(H[3], uG[3], dG); dO = fmaf(H[3], uO[3], dO);                \
        dI = fmaf(H[4], uI[4], dI); dF = fmaf(H[4], uF[4], dF);                \
        dG = fmaf(H[4], uG[4], dG); dO = fmaf(H[4], uO[4], dO);                \
        dI = fmaf(H[5], uI[5], dI); dF = fmaf(H[5], uF[5], dF);                \
        dG = fmaf(H[5], uG[5], dG); dO = fmaf(H[5], uO[5], dO);                \
        dI = fmaf(H[6], uI[6], dI); dF = fmaf(H[6], uF[6], dF);                \
        dG = fmaf(H[6], uG[6], dG); dO = fmaf(H[6], uO[6], dO);                \
        dI = fmaf(H[7], uI[7], dI); dF = fmaf(H[7], uF[7], dF);                \
        dG = fmaf(H[7], uG[7], dG); dO = fmaf(H[7], uO[7], dO);                \
        float GI = done ? gi : (gi + dI);                                      \
        float GF = done ? gf : (gf + dF);                                      \
        float GG = done ? gg : (gg + dG);                                      \
        float GO = done ? go : (go + dO);                                      \
        float cin = done ? 0.f : C;                                            \
        float i_ = 1.f / (1.f + __expf(-GI));                                  \
        float f_ = 1.f / (1.f + __expf(-GF));                                  \
        float g_ = 2.f / (1.f + __expf(-2.f * GG)) - 1.f;                      \
        float o_ = 1.f / (1.f + __expf(-GO));                                  \
        float c2 = fmaf(f_, cin, i_ * g_);                                     \
        C = c2;                                                                \
        float th = 2.f / (1.f + __expf(-2.f * c2)) - 1.f;                      \
        float h2 = o_ * th;                                                    \
        H[0] = __shfl(h2, gb | 0, 64); H[1] = __shfl(h2, gb | 1, 64);          \
        H[2] = __shfl(h2, gb | 2, 64); H[3] = __shfl(h2, gb | 3, 64);          \
        H[4] = __shfl(h2, gb | 4, 64); H[5] = __shfl(h2, gb | 5, 64);          \
        H[6] = __shfl(h2, gb | 6, 64); H[7] = __shfl(h2, gb | 7, 64);          \
        FD = (done && FD == SEGLEN) ? (K) : FD;                                \
        float o0 = hb0, o1 = hb1, o2 = hb2;                                    \
        o0 = fmaf(H[0], hw0[0], o0); o1 = fmaf(H[0], hw1[0], o1);              \
        o2 = fmaf(H[0], hw2[0], o2);                                           \
        o0 = fmaf(H[1], hw0[1], o0); o1 = fmaf(H[1], hw1[1], o1);              \
        o2 = fmaf(H[1], hw2[1], o2);                                           \
        o0 = fmaf(H[2], hw0[2], o0); o1 = fmaf(H[2], hw1[2], o1);              \
        o2 = fmaf(H[2], hw2[2], o2);                                           \
        o0 = fmaf(H[3], hw0[3], o0); o1 = fmaf(H[3], hw1[3], o1);              \
        o2 = fmaf(H[3], hw2[3], o2);                                           \
        o0 = fmaf(H[4], hw0[4], o0); o1 = fmaf(H[4], hw1[4], o1);              \
        o2 = fmaf(H[4], hw2[4], o2);                                           \
        o0 = fmaf(H[5], hw0[5], o0); o1 = fmaf(H[5], hw1[5], o1);              \
        o2 = fmaf(H[5], hw2[5], o2);                                           \
        o0 = fmaf(H[6], hw0[6], o0); o1 = fmaf(H[6], hw1[6], o1);              \
        o2 = fmaf(H[6], hw2[6], o2);                                           \
        o0 = fmaf(H[7], hw0[7], o0); o1 = fmaf(H[7], hw1[7], o1);              \
        o2 = fmaf(H[7], hw2[7], o2);                                           \
        OUTA[j] = o0; OUTA[8 + j] = o1;                                        \
        if (j < 2) OUTA[16 + j] = o2; else if (j == 2) *OUTV = o2;             \
        OUTA += (size_t)T_DIM * 18; OUTV += T_DIM;                             \
    }

// ---------------------------------------------------------------------------
// Pass 1: segmented scan, TWO independent chains per wave (tb and tb+256,
// same segment s -> shared weights, interleaved steps hide shfl/exp latency).
// Grid 2048 x 64. No min-waves hint (R11 lesson: it forced VGPR=64 -> spills).
// ---------------------------------------------------------------------------
__global__ __launch_bounds__(64) void pass1_kernel(
    const float* __restrict__ x2t, const int* __restrict__ dones_t,
    const float* __restrict__ hx,
    const float* __restrict__ Wih, const float* __restrict__ bih,
    const float* __restrict__ Whh, const float* __restrict__ bhh,
    const float* __restrict__ Wa, const float* __restrict__ ba,
    const float* __restrict__ Wv, const float* __restrict__ bv,
    float* __restrict__ out,
    float* __restrict__ carryH, float* __restrict__ carryC,
    int* __restrict__ fdbuf)
{
    int lane = threadIdx.x;
    int col  = lane >> 3;
    int j    = lane & 7;
    int gb   = lane & 56;
    int s    = blockIdx.x >> 8;          // 0..7
    int tbA  = blockIdx.x & 255;
    int tbB  = tbA + 256;
    int tA   = tbA * 8 + col;
    int tB   = tbB * 8 + col;
    int b0   = s * SEGLEN;

    LOAD_LSTM_WEIGHTS

    float hA[8], hB[8]; float cA, cB;
    if (s == 0) {
#pragma unroll
        for (int m = 0; m < 8; ++m) { hA[m] = hx[tA * 8 + m]; hB[m] = hx[tB * 8 + m]; }
        cA = hx[T_DIM * 8 + tA * 8 + j];
        cB = hx[T_DIM * 8 + tB * 8 + j];
    } else {
#pragma unroll
        for (int m = 0; m < 8; ++m) { hA[m] = 0.f; hB[m] = 0.f; }
        cA = 0.f; cB = 0.f;
    }

    const float4* xtA = (const float4*)x2t + (size_t)tbA * 4096 + col * 2;
    const float4* xtB = (const float4*)x2t + (size_t)tbB * 4096 + col * 2;
    const int*    dtA = dones_t + (size_t)tbA * (B_DIM * 8) + col;
    const int*    dtB = dones_t + (size_t)tbB * (B_DIM * 8) + col;
    float* outAA = out + ((size_t)b0 * T_DIM + tA) * 18;
    float* outVA = out + (size_t)18 * B_DIM * T_DIM + (size_t)b0 * T_DIM + tA;
    float* outAB = out + ((size_t)b0 * T_DIM + tB) * 18;
    float* outVB = out + (size_t)18 * B_DIM * T_DIM + (size_t)b0 * T_DIM + tB;
    int fdA = SEGLEN, fdB = SEGLEN;

    // 1-deep prefetch per chain (interleaved 2-chain body covers latency)
    int dnA = dtA[(size_t)b0 * 8];
    float4 xaA = xtA[(size_t)b0 * 16], xvA = xtA[(size_t)b0 * 16 + 1];
    int dnB = dtB[(size_t)b0 * 8];
    float4 xaB = xtB[(size_t)b0 * 16], xvB = xtB[(size_t)b0 * 16 + 1];

    for (int k = 0; k < SEGLEN; ++k) {
        P1STEP(k, hA, cA, fdA, dnA, xaA, xvA, dtA, xtA, outAA, outVA)
        P1STEP(k, hB, cB, fdB, dnB, xaB, xvB, dtB, xtB, outAB, outVB)
    }

    carryH[((size_t)s * T_DIM + tA) * 8 + j] = hA[j];
    carryC[((size_t)s * T_DIM + tA) * 8 + j] = cA;
    carryH[((size_t)s * T_DIM + tB) * 8 + j] = hB[j];
    carryC[((size_t)s * T_DIM + tB) * 8 + j] = cB;
    if (j == 0) {
        fdbuf[(size_t)s * T_DIM + tA] = fdA;
        fdbuf[(size_t)s * T_DIM + tB] = fdB;
    }
}

// ---------------------------------------------------------------------------
// Pass 2: serial over segments 1..7; recompute steps [0, fd) with true carry,
// then adopt pass-1's exact carry. Verified R9/R10 logic.
// ---------------------------------------------------------------------------
__global__ __launch_bounds__(64) void pass2_kernel(
    const float* __restrict__ x2t,
    const float* __restrict__ Wih, const float* __restrict__ bih,
    const float* __restrict__ Whh, const float* __restrict__ bhh,
    const float* __restrict__ Wa, const float* __restrict__ ba,
    const float* __restrict__ Wv, const float* __restrict__ bv,
    float* __restrict__ out,
    const float* __restrict__ carryH, const float* __restrict__ carryC,
    const int* __restrict__ fdbuf)
{
    int lane = threadIdx.x;
    int col  = lane >> 3;
    int j    = lane & 7;
    int gb   = lane & 56;
    int tb   = blockIdx.x;
    int t    = tb * 8 + col;

    LOAD_LSTM_WEIGHTS

    float h[8]; float c;
#pragma unroll
    for (int m = 0; m < 8; ++m) h[m] = carryH[(size_t)t * 8 + m];
    c = carryC[(size_t)t * 8 + j];

    const float4* xt4 = (const float4*)x2t + (size_t)tb * 4096 + col * 2;

    for (int s = 1; s < NSEG; ++s) {
        int fd = fdbuf[(size_t)s * T_DIM + t];
        int wmax = fd;
#pragma unroll
        for (int d = 1; d < 64; d <<= 1) {
            int o = __shfl_xor(wmax, d, 64);
            wmax = (o > wmax) ? o : wmax;
        }
        size_t bbase = (size_t)s * SEGLEN;

        float4 cxa = xt4[bbase * 16], cxv = xt4[bbase * 16 + 1];
        for (int k = 0; k < wmax; ++k) {
            bool act = (k < fd);
            float4 a = cxa, v = cxv;
            int kn = k + 1; kn = (kn > SEGLEN - 1) ? (SEGLEN - 1) : kn;
            cxa = xt4[(bbase + kn) * 16];
            cxv = xt4[(bbase + kn) * 16 + 1];
            float gi = bI, gf = bF, gg = bG, go = bO;
            gi = fmaf(a.x, wI[0], gi); gi = fmaf(a.y, wI[1], gi);
            gi = fmaf(a.z, wI[2], gi); gi = fmaf(a.w, wI[3], gi);
            gi = fmaf(v.x, wI[4], gi); gi = fmaf(v.y, wI[5], gi);
            gi = fmaf(v.z, wI[6], gi); gi = fmaf(v.w, wI[7], gi);
            gf = fmaf(a.x, wF[0], gf); gf = fmaf(a.y, wF[1], gf);
            gf = fmaf(a.z, wF[2], gf); gf = fmaf(a.w, wF[3], gf);
            gf = fmaf(v.x, wF[4], gf); gf = fmaf(v.y, wF[5], gf);
            gf = fmaf(v.z, wF[6], gf); gf = fmaf(v.w, wF[7], gf);
            gg = fmaf(a.x, wG[0], gg); gg = fmaf(a.y, wG[1], gg);
            gg = fmaf(a.z, wG[2], gg); gg = fmaf(a.w, wG[3], gg);
            gg = fmaf(v.x, wG[4], gg); gg = fmaf(v.y, wG[5], gg);
            gg = fmaf(v.z, wG[6], gg); gg = fmaf(v.w, wG[7], gg);
            go = fmaf(a.x, wO[0], go); go = fmaf(a.y, wO[1], go);
            go = fmaf(a.z, wO[2], go); go = fmaf(a.w, wO[3], go);
            go = fmaf(v.x, wO[4], go); go = fmaf(v.y, wO[5], go);
            go = fmaf(v.z, wO[6], go); go = fmaf(v.w, wO[7], go);
            float dI = h[0] * uI[0], dF = h[0] * uF[0];
            float dG = h[0] * uG[0], dO = h[0] * uO[0];
            dI = fmaf(h[1], uI[1], dI); dF = fmaf(h[1], uF[1], dF);
            dG = fmaf(h[1], uG[1], dG); dO = fmaf(h[1], uO[1], dO);
            dI = fmaf(h[2], uI[2], dI); dF = fmaf(h[2], uF[2], dF);
            dG = fmaf(h[2], uG[2], dG); dO = fmaf(h[2], uO[2], dO);
            dI = fmaf(h[3], uI[3], dI); dF = fmaf(h[3], uF[3], dF);
            dG = fmaf(h[3], uG[3], dG); dO = fmaf(h[3], uO[3], dO);
            dI = fmaf(h[4], uI[4], dI); dF = fmaf(h[4], uF[4], dF);
            dG = fmaf(h[4], uG[4], dG); dO = fmaf(h[4], uO[4], dO);
            dI = fmaf(h[5], uI[5], dI); dF = fmaf(h[5], uF[5], dF);
            dG = fmaf(h[5], uG[5], dG); dO = fmaf(h[5], uO[5], dO);
            dI = fmaf(h[6], uI[6], dI); dF = fmaf(h[6], uF[6], dF);
            dG = fmaf(h[6], uG[6], dG); dO = fmaf(h[6], uO[6], dO);
            dI = fmaf(h[7], uI[7], dI); dF = fmaf(h[7], uF[7], dF);
            dG = fmaf(h[7], uG[7], dG); dO = fmaf(h[7], uO[7], dO);
            float GI = gi + dI, GF = gf + dF, GG = gg + dG, GO = go + dO;
            float i_ = 1.f / (1.f + __expf(-GI));
            float f_ = 1.f / (1.f + __expf(-GF));
            float g_ = 2.f / (1.f + __expf(-2.f * GG)) - 1.f;
            float o_ = 1.f / (1.f + __expf(-GO));
            float c2 = fmaf(f_, c, i_ * g_);
            float th = 2.f / (1.f + __expf(-2.f * c2)) - 1.f;
            float h2 = o_ * th;
            c = act ? c2 : c;
            float n0 = __shfl(h2, gb | 0, 64), n1 = __shfl(h2, gb | 1, 64);
            float n2 = __shfl(h2, gb | 2, 64), n3 = __shfl(h2, gb | 3, 64);
            float n4 = __shfl(h2, gb | 4, 64), n5 = __shfl(h2, gb | 5, 64);
            float n6 = __shfl(h2, gb | 6, 64), n7 = __shfl(h2, gb | 7, 64);
            h[0] = act ? n0 : h[0]; h[1] = act ? n1 : h[1];
            h[2] = act ? n2 : h[2]; h[3] = act ? n3 : h[3];
            h[4] = act ? n4 : h[4]; h[5] = act ? n5 : h[5];
            h[6] = act ? n6 : h[6]; h[7] = act ? n7 : h[7];
            float o0 = hb0, o1 = hb1, o2 = hb2;
            o0 = fmaf(h[0], hw0[0], o0); o1 = fmaf(h[0], hw1[0], o1);
            o2 = fmaf(h[0], hw2[0], o2);
            o0 = fmaf(h[1], hw0[1], o0); o1 = fmaf(h[1], hw1[1], o1);
            o2 = fmaf(h[1], hw2[1], o2);
            o0 = fmaf(h[2], hw0[2], o0); o1 = fmaf(h[2], hw1[2], o1);
            o2 = fmaf(h[2], hw2[2], o2);
            o0 = fmaf(h[3], hw0[3], o0); o1 = fmaf(h[3], hw1[3], o1);
            o2 = fmaf(h[3], hw2[3], o2);
            o0 = fmaf(h[4], hw0[4], o0); o1 = fmaf(h[4], hw1[4], o1);
            o2 = fmaf(h[4], hw2[4], o2);
            o0 = fmaf(h[5], hw0[5], o0); o1 = fmaf(h[5], hw1[5], o1);
            o2 = fmaf(h[5], hw2[5], o2);
            o0 = fmaf(h[6], hw0[6], o0); o1 = fmaf(h[6], hw1[6], o1);
            o2 = fmaf(h[6], hw2[6], o2);
            o0 = fmaf(h[7], hw0[7], o0); o1 = fmaf(h[7], hw1[7], o1);
            o2 = fmaf(h[7], hw2[7], o2);
            if (act) {
                float* outA = out + ((bbase + k) * T_DIM + t) * 18;
                outA[j] = o0; outA[8 + j] = o1;
                if (j < 2) outA[16 + j] = o2;
                else if (j == 2)
                    out[(size_t)18 * B_DIM * T_DIM + (bbase + k) * T_DIM + t] = o2;
            }
        }
        if (fd < SEGLEN) {
#pragma unroll
            for (int m = 0; m < 8; ++m)
                h[m] = carryH[((size_t)s * T_DIM + t) * 8 + m];
            c = carryC[((size_t)s * T_DIM + t) * 8 + j];
        }
    }
}

// ---------------------------------------------------------------------------
extern "C" void kernel_launch(void* const* d_in, const int* in_sizes, int n_in,
                              void* d_out, int out_size, void* d_ws, size_t ws_size,
                              hipStream_t stream) {
    (void)in_sizes; (void)n_in; (void)out_size; (void)ws_size;
    const float* states = (const float*)d_in[0];
    const int*   dones  = (const int*)d_in[1];
    const float* hx     = (const float*)d_in[2];
    const float* W1     = (const float*)d_in[3];
    const float* b1     = (const float*)d_in[4];
    const float* W2     = (const float*)d_in[5];
    const float* b2     = (const float*)d_in[6];
    const float* Wih    = (const float*)d_in[7];
    const float* bih    = (const float*)d_in[8];
    const float* Whh    = (const float*)d_in[9];
    const float* bhh    = (const float*)d_in[10];
    const float* Wa     = (const float*)d_in[11];
    const float* ba     = (const float*)d_in[12];
    const float* Wv     = (const float*)d_in[13];
    const float* bv     = (const float*)d_in[14];
    float* out = (float*)d_out;

    float* x2t     = (float*)d_ws;                               // 32 MiB
    int*   dones_t = (int*)((char*)d_ws + (32u << 20));          // 4 MiB
    float* carryH  = (float*)((char*)d_ws + (36u << 20));        // 1 MiB
    float* carryC  = (float*)((char*)d_ws + (37u << 20));        // 1 MiB
    int*   fdbuf   = (int*)((char*)d_ws + (38u << 20));          // 128 KiB

    mlp_kernel<<<(B_DIM * T_DIM) / 64, 256, 0, stream>>>(states, dones, W1, b1, W2, b2,
                                                         x2t, dones_t);
    pass1_kernel<<<(NSEG * 512) / 2, 64, 0, stream>>>(x2t, dones_t, hx,
                                                      Wih, bih, Whh, bhh, Wa, ba, Wv, bv,
                                                      out, carryH, carryC, fdbuf);
    pass2_kernel<<<512, 64, 0, stream>>>(x2t, Wih, bih, Whh, bhh, Wa, ba, Wv, bv,
                                         out, carryH, carryC, fdbuf);
}

// Round 13
// 136.093 us; speedup vs baseline: 2.1836x; 1.1124x over previous
//
#include <hip/hip_runtime.h>

#define T_DIM 4096
#define B_DIM 256
#define NSEG 8
#define SEGLEN 32
// N_OBS=64, H=8, N_ACT=18

// fast sigmoid/tanh: v_rcp_f32 (~1 ULP) instead of IEEE division sequence
#define SIGM(X)  __builtin_amdgcn_rcpf(1.f + __expf(-(X)))
#define TANH(X)  fmaf(2.f, __builtin_amdgcn_rcpf(1.f + __expf(-2.f * (X))), -1.f)

// ws layout: x2t     32 MiB @ 0        float, [tb][b][ti][8]
//            dones_t  4 MiB @ 32 MiB   int,   [tb][b][ti]
//            carryH   1 MiB @ 36 MiB   float, [s][t][8]
//            carryC   1 MiB @ 37 MiB
//            fdbuf  128 KiB @ 38 MiB   int,   [s][t]

// ---------------------------------------------------------------------------
// Kernel A: fused MLP  states(B,T,64) -> x2t transposed; stages dones_t.
// Verified R7/R10; ~50-55 us = its traffic floor. Unchanged.
// ---------------------------------------------------------------------------
__global__ __launch_bounds__(256) void mlp_kernel(
    const float* __restrict__ states,
    const int* __restrict__ dones,
    const float* __restrict__ W1, const float* __restrict__ b1,
    const float* __restrict__ W2, const float* __restrict__ b2,
    float* __restrict__ x2t, int* __restrict__ dones_t)
{
    __shared__ float4 w1s4[4][16];
    __shared__ float  w2s[8][4];
    __shared__ float  b1s[4];
    __shared__ float  b2s[8];
    __shared__ float4 stage[4][16 * 17];

    int tid = threadIdx.x;
    ((float*)w1s4)[tid] = W1[tid];
    if (tid < 32) ((float*)w2s)[tid] = W2[tid];
    if (tid < 4)  b1s[tid] = b1[tid];
    if (tid >= 8 && tid < 16) b2s[tid - 8] = b2[tid - 8];

    if (tid < 64) {
        int r2 = blockIdx.x * 64 + tid;
        int b = r2 >> 12, t = r2 & 4095;
        dones_t[(size_t)(t >> 3) * (B_DIM * 8) + b * 8 + (t & 7)] = dones[r2];
    }

    int w = tid >> 6;
    int l = tid & 63;

    const float4* src4 = (const float4*)states;
    size_t base_f4 = ((size_t)blockIdx.x * 64 + (size_t)w * 16) * 16;
#pragma unroll
    for (int k = 0; k < 4; ++k) {
        int idx = k * 64 + l;
        int row = idx >> 4, m = idx & 15;
        stage[w][row * 17 + m] = src4[base_f4 + idx];
    }
    __syncthreads();

    int rl = l >> 2;
    int q  = l & 3;
    const float4* rowp = &stage[w][rl * 17];

    float a0 = 0.f, a1 = 0.f, a2 = 0.f, a3 = 0.f;
#pragma unroll
    for (int kk = 0; kk < 4; ++kk) {
        float4 v = rowp[q * 4 + kk];
        float4 w0 = w1s4[0][q * 4 + kk];
        float4 w1v = w1s4[1][q * 4 + kk];
        float4 w2v = w1s4[2][q * 4 + kk];
        float4 w3v = w1s4[3][q * 4 + kk];
        a0 = fmaf(v.x, w0.x, a0); a0 = fmaf(v.y, w0.y, a0);
        a0 = fmaf(v.z, w0.z, a0); a0 = fmaf(v.w, w0.w, a0);
        a1 = fmaf(v.x, w1v.x, a1); a1 = fmaf(v.y, w1v.y, a1);
        a1 = fmaf(v.z, w1v.z, a1); a1 = fmaf(v.w, w1v.w, a1);
        a2 = fmaf(v.x, w2v.x, a2); a2 = fmaf(v.y, w2v.y, a2);
        a2 = fmaf(v.z, w2v.z, a2); a2 = fmaf(v.w, w2v.w, a2);
        a3 = fmaf(v.x, w3v.x, a3); a3 = fmaf(v.y, w3v.y, a3);
        a3 = fmaf(v.z, w3v.z, a3); a3 = fmaf(v.w, w3v.w, a3);
    }
    a0 += __shfl_xor(a0, 1, 64); a1 += __shfl_xor(a1, 1, 64);
    a2 += __shfl_xor(a2, 1, 64); a3 += __shfl_xor(a3, 1, 64);
    a0 += __shfl_xor(a0, 2, 64); a1 += __shfl_xor(a1, 2, 64);
    a2 += __shfl_xor(a2, 2, 64); a3 += __shfl_xor(a3, 2, 64);

    a0 = fmaxf(a0 + b1s[0], 0.f);
    a1 = fmaxf(a1 + b1s[1], 0.f);
    a2 = fmaxf(a2 + b1s[2], 0.f);
    a3 = fmaxf(a3 + b1s[3], 0.f);

    int h0 = 2 * q, h1 = 2 * q + 1;
    float s0 = b2s[h0];
    s0 = fmaf(a0, w2s[h0][0], s0); s0 = fmaf(a1, w2s[h0][1], s0);
    s0 = fmaf(a2, w2s[h0][2], s0); s0 = fmaf(a3, w2s[h0][3], s0);
    float s1 = b2s[h1];
    s1 = fmaf(a0, w2s[h1][0], s1); s1 = fmaf(a1, w2s[h1][1], s1);
    s1 = fmaf(a2, w2s[h1][2], s1); s1 = fmaf(a3, w2s[h1][3], s1);
    s0 = fmaxf(s0, 0.f);
    s1 = fmaxf(s1, 0.f);

    int r = blockIdx.x * 64 + w * 16 + rl;
    int b = r >> 12, t = r & 4095;
    size_t f2i = (size_t)(t >> 3) * 8192 + (size_t)b * 32 + (t & 7) * 4 + q;
    ((float2*)x2t)[f2i] = make_float2(s0, s1);
}

// ---------------------------------------------------------------------------
// Shared LSTM pieces (x read directly from x2t).
// ---------------------------------------------------------------------------
#define LOAD_LSTM_WEIGHTS                                                      \
    float wI[8], wF[8], wG[8], wO[8], uI[8], uF[8], uG[8], uO[8];              \
    _Pragma("unroll") for (int k = 0; k < 8; ++k) {                            \
        wI[k] = Wih[j * 8 + k];        uI[k] = Whh[j * 8 + k];                 \
        wF[k] = Wih[(8 + j) * 8 + k];  uF[k] = Whh[(8 + j) * 8 + k];           \
        wG[k] = Wih[(16 + j) * 8 + k]; uG[k] = Whh[(16 + j) * 8 + k];          \
        wO[k] = Wih[(24 + j) * 8 + k]; uO[k] = Whh[(24 + j) * 8 + k];          \
    }                                                                          \
    float bI = bih[j] + bhh[j],      bF = bih[8 + j] + bhh[8 + j];             \
    float bG = bih[16 + j] + bhh[16 + j], bO = bih[24 + j] + bhh[24 + j];      \
    float hw0[8], hw1[8], hw2[8];                                              \
    float hb0 = ba[j], hb1 = ba[8 + j], hb2 = 0.f;                             \
    _Pragma("unroll") for (int k = 0; k < 8; ++k) {                            \
        hw0[k] = Wa[j * 8 + k]; hw1[k] = Wa[(8 + j) * 8 + k]; hw2[k] = 0.f;    \
    }                                                                          \
    if (j < 2) {                                                               \
        _Pragma("unroll") for (int k = 0; k < 8; ++k) hw2[k] = Wa[(16+j)*8+k]; \
        hb2 = ba[16 + j];                                                      \
    } else if (j == 2) {                                                       \
        _Pragma("unroll") for (int k = 0; k < 8; ++k) hw2[k] = Wv[k];          \
        hb2 = bv[0];                                                           \
    }

#define CORE_X(DONEE, XA, XB)                                                  \
        float gi = bI, gf = bF, gg = bG, go = bO;                              \
        gi = fmaf(XA.x, wI[0], gi); gi = fmaf(XA.y, wI[1], gi);                \
        gi = fmaf(XA.z, wI[2], gi); gi = fmaf(XA.w, wI[3], gi);                \
        gi = fmaf(XB.x, wI[4], gi); gi = fmaf(XB.y, wI[5], gi);                \
        gi = fmaf(XB.z, wI[6], gi); gi = fmaf(XB.w, wI[7], gi);                \
        gf = fmaf(XA.x, wF[0], gf); gf = fmaf(XA.y, wF[1], gf);                \
        gf = fmaf(XA.z, wF[2], gf); gf = fmaf(XA.w, wF[3], gf);                \
        gf = fmaf(XB.x, wF[4], gf); gf = fmaf(XB.y, wF[5], gf);                \
        gf = fmaf(XB.z, wF[6], gf); gf = fmaf(XB.w, wF[7], gf);                \
        gg = fmaf(XA.x, wG[0], gg); gg = fmaf(XA.y, wG[1], gg);                \
        gg = fmaf(XA.z, wG[2], gg); gg = fmaf(XA.w, wG[3], gg);                \
        gg = fmaf(XB.x, wG[4], gg); gg = fmaf(XB.y, wG[5], gg);                \
        gg = fmaf(XB.z, wG[6], gg); gg = fmaf(XB.w, wG[7], gg);                \
        go = fmaf(XA.x, wO[0], go); go = fmaf(XA.y, wO[1], go);                \
        go = fmaf(XA.z, wO[2], go); go = fmaf(XA.w, wO[3], go);                \
        go = fmaf(XB.x, wO[4], go); go = fmaf(XB.y, wO[5], go);                \
        go = fmaf(XB.z, wO[6], go); go = fmaf(XB.w, wO[7], go);                \
        float dI = h[0] * uI[0], dF = h[0] * uF[0];                            \
        float dG = h[0] * uG[0], dO = h[0] * uO[0];                            \
        dI = fmaf(h[1], uI[1], dI); dF = fmaf(h[1], uF[1], dF);                \
        dG = fmaf(h[1], uG[1], dG); dO = fmaf(h[1], uO[1], dO);                \
        dI = fmaf(h[2], uI[2], dI); dF = fmaf(h[2], uF[2], dF);                \
        dG = fmaf(h[2], uG[2], dG); dO = fmaf(h[2], uO[2], dO);                \
        dI = fmaf(h[3], uI[3], dI); dF = fmaf(h[3], uF[3], dF);                \
        dG = fmaf(h[3], uG[3], dG); dO = fmaf(h[3], uO[3], dO);                \
        dI = fmaf(h[4], uI[4], dI); dF = fmaf(h[4], uF[4], dF);                \
        dG = fmaf(h[4], uG[4], dG); dO = fmaf(h[4], uO[4], dO);                \
        dI = fmaf(h[5], uI[5], dI); dF = fmaf(h[5], uF[5], dF);                \
        dG = fmaf(h[5], uG[5], dG); dO = fmaf(h[5], uO[5], dO);                \
        dI = fmaf(h[6], uI[6], dI); dF = fmaf(h[6], uF[6], dF);                \
        dG = fmaf(h[6], uG[6], dG); dO = fmaf(h[6], uO[6], dO);                \
        dI = fmaf(h[7], uI[7], dI); dF = fmaf(h[7], uF[7], dF);                \
        dG = fmaf(h[7], uG[7], dG); dO = fmaf(h[7], uO[7], dO);                \
        float GI = (DONEE) ? gi : (gi + dI);                                   \
        float GF = (DONEE) ? gf : (gf + dF);                                   \
        float GG = (DONEE) ? gg : (gg + dG);                                   \
        float GO = (DONEE) ? go : (go + dO);                                   \
        float cin = (DONEE) ? 0.f : c;                                         \
        float i_ = SIGM(GI);                                                   \
        float f_ = SIGM(GF);                                                   \
        float g_ = TANH(GG);                                                   \
        float o_ = SIGM(GO);                                                   \
        float c2 = fmaf(f_, cin, i_ * g_);                                     \
        float th = TANH(c2);                                                   \
        float h2 = o_ * th;

#define HEADS                                                                  \
        float o0 = hb0, o1 = hb1, o2 = hb2;                                    \
        o0 = fmaf(h[0], hw0[0], o0); o1 = fmaf(h[0], hw1[0], o1);              \
        o2 = fmaf(h[0], hw2[0], o2);                                           \
        o0 = fmaf(h[1], hw0[1], o0); o1 = fmaf(h[1], hw1[1], o1);              \
        o2 = fmaf(h[1], hw2[1], o2);                                           \
        o0 = fmaf(h[2], hw0[2], o0); o1 = fmaf(h[2], hw1[2], o1);              \
        o2 = fmaf(h[2], hw2[2], o2);                                           \
        o0 = fmaf(h[3], hw0[3], o0); o1 = fmaf(h[3], hw1[3], o1);              \
        o2 = fmaf(h[3], hw2[3], o2);                                           \
        o0 = fmaf(h[4], hw0[4], o0); o1 = fmaf(h[4], hw1[4], o1);              \
        o2 = fmaf(h[4], hw2[4], o2);                                           \
        o0 = fmaf(h[5], hw0[5], o0); o1 = fmaf(h[5], hw1[5], o1);              \
        o2 = fmaf(h[5], hw2[5], o2);                                           \
        o0 = fmaf(h[6], hw0[6], o0); o1 = fmaf(h[6], hw1[6], o1);              \
        o2 = fmaf(h[6], hw2[6], o2);                                           \
        o0 = fmaf(h[7], hw0[7], o0); o1 = fmaf(h[7], hw1[7], o1);              \
        o2 = fmaf(h[7], hw2[7], o2);

// ---------------------------------------------------------------------------
// Pass 1: segmented scan over x2t (R10-verified structure, 4-deep prefetch).
// ---------------------------------------------------------------------------
__global__ __launch_bounds__(64) void pass1_kernel(
    const float* __restrict__ x2t, const int* __restrict__ dones_t,
    const float* __restrict__ hx,
    const float* __restrict__ Wih, const float* __restrict__ bih,
    const float* __restrict__ Whh, const float* __restrict__ bhh,
    const float* __restrict__ Wa, const float* __restrict__ ba,
    const float* __restrict__ Wv, const float* __restrict__ bv,
    float* __restrict__ out,
    float* __restrict__ carryH, float* __restrict__ carryC,
    int* __restrict__ fdbuf)
{
    int lane = threadIdx.x;
    int col  = lane >> 3;
    int j    = lane & 7;
    int gb   = lane & 56;
    int s    = blockIdx.x >> 9;
    int tb   = blockIdx.x & 511;
    int t    = tb * 8 + col;
    int b0   = s * SEGLEN;

    LOAD_LSTM_WEIGHTS

    float h[8]; float c;
    if (s == 0) {
#pragma unroll
        for (int m = 0; m < 8; ++m) h[m] = hx[t * 8 + m];
        c = hx[T_DIM * 8 + t * 8 + j];
    } else {
#pragma unroll
        for (int m = 0; m < 8; ++m) h[m] = 0.f;
        c = 0.f;
    }

    const float4* xt4 = (const float4*)x2t + (size_t)tb * 4096 + col * 2;
    const int*    dtp = dones_t + (size_t)tb * (B_DIM * 8) + col;
    float* outA = out + ((size_t)b0 * T_DIM + t) * 18;
    float* outV = out + (size_t)18 * B_DIM * T_DIM + (size_t)b0 * T_DIM + t;
    int fd = SEGLEN;

    int dn0, dn1, dn2, dn3;
    float4 xa0, xv0, xa1, xv1, xa2, xv2, xa3, xv3;
#define PF(I) \
    dn##I = dtp[(size_t)(b0 + (I)) * 8]; \
    xa##I = xt4[(size_t)(b0 + (I)) * 16]; \
    xv##I = xt4[(size_t)(b0 + (I)) * 16 + 1];
    PF(0) PF(1) PF(2) PF(3)
#undef PF

#define P1STEP(KK, DN, XA, XV)                                                 \
    {                                                                          \
        int done = DN; float4 xa = XA, xv = XV;                                \
        int kp = (KK) + 4; kp = (kp > SEGLEN - 1) ? (SEGLEN - 1) : kp;         \
        DN = dtp[(size_t)(b0 + kp) * 8];                                       \
        XA = xt4[(size_t)(b0 + kp) * 16];                                      \
        XV = xt4[(size_t)(b0 + kp) * 16 + 1];                                  \
        CORE_X(done, xa, xv)                                                   \
        c = c2;                                                                \
        h[0] = __shfl(h2, gb | 0, 64); h[1] = __shfl(h2, gb | 1, 64);          \
        h[2] = __shfl(h2, gb | 2, 64); h[3] = __shfl(h2, gb | 3, 64);          \
        h[4] = __shfl(h2, gb | 4, 64); h[5] = __shfl(h2, gb | 5, 64);          \
        h[6] = __shfl(h2, gb | 6, 64); h[7] = __shfl(h2, gb | 7, 64);          \
        fd = (done && fd == SEGLEN) ? (KK) : fd;                               \
        HEADS                                                                  \
        outA[j] = o0; outA[8 + j] = o1;                                        \
        if (j < 2) outA[16 + j] = o2; else if (j == 2) *outV = o2;             \
        outA += (size_t)T_DIM * 18; outV += T_DIM;                             \
    }

    for (int k0 = 0; k0 < SEGLEN; k0 += 4) {
        P1STEP(k0 + 0, dn0, xa0, xv0);
        P1STEP(k0 + 1, dn1, xa1, xv1);
        P1STEP(k0 + 2, dn2, xa2, xv2);
        P1STEP(k0 + 3, dn3, xa3, xv3);
    }
#undef P1STEP

    carryH[((size_t)s * T_DIM + t) * 8 + j] = h[j];
    carryC[((size_t)s * T_DIM + t) * 8 + j] = c;
    if (j == 0) fdbuf[(size_t)s * T_DIM + t] = fd;
}

// ---------------------------------------------------------------------------
// Pass 2: serial over segments; recompute steps [0, fd) with the true carry,
// then adopt pass-1's exact carry. R9/R10-verified logic + rcp activations.
// ---------------------------------------------------------------------------
__global__ __launch_bounds__(64) void pass2_kernel(
    const float* __restrict__ x2t,
    const float* __restrict__ Wih, const float* __restrict__ bih,
    const float* __restrict__ Whh, const float* __restrict__ bhh,
    const float* __restrict__ Wa, const float* __restrict__ ba,
    const float* __restrict__ Wv, const float* __restrict__ bv,
    float* __restrict__ out,
    const float* __restrict__ carryH, const float* __restrict__ carryC,
    const int* __restrict__ fdbuf)
{
    int lane = threadIdx.x;
    int col  = lane >> 3;
    int j    = lane & 7;
    int gb   = lane & 56;
    int tb   = blockIdx.x;
    int t    = tb * 8 + col;

    LOAD_LSTM_WEIGHTS

    float h[8]; float c;
#pragma unroll
    for (int m = 0; m < 8; ++m) h[m] = carryH[(size_t)t * 8 + m];
    c = carryC[(size_t)t * 8 + j];

    const float4* xt4 = (const float4*)x2t + (size_t)tb * 4096 + col * 2;

    for (int s = 1; s < NSEG; ++s) {
        int fd = fdbuf[(size_t)s * T_DIM + t];
        int wmax = fd;
#pragma unroll
        for (int d = 1; d < 64; d <<= 1) {
            int o = __shfl_xor(wmax, d, 64);
            wmax = (o > wmax) ? o : wmax;
        }
        size_t bbase = (size_t)s * SEGLEN;

        float4 cxa = xt4[bbase * 16], cxv = xt4[bbase * 16 + 1];
        for (int k = 0; k < wmax; ++k) {
            bool act = (k < fd);
            float4 xa = cxa, xv = cxv;
            int kn = k + 1; kn = (kn > SEGLEN - 1) ? (SEGLEN - 1) : kn;
            cxa = xt4[(bbase + kn) * 16];
            cxv = xt4[(bbase + kn) * 16 + 1];
            CORE_X(0, xa, xv)
            c = act ? c2 : c;
            float n0 = __shfl(h2, gb | 0, 64), n1 = __shfl(h2, gb | 1, 64);
            float n2 = __shfl(h2, gb | 2, 64), n3 = __shfl(h2, gb | 3, 64);
            float n4 = __shfl(h2, gb | 4, 64), n5 = __shfl(h2, gb | 5, 64);
            float n6 = __shfl(h2, gb | 6, 64), n7 = __shfl(h2, gb | 7, 64);
            h[0] = act ? n0 : h[0]; h[1] = act ? n1 : h[1];
            h[2] = act ? n2 : h[2]; h[3] = act ? n3 : h[3];
            h[4] = act ? n4 : h[4]; h[5] = act ? n5 : h[5];
            h[6] = act ? n6 : h[6]; h[7] = act ? n7 : h[7];
            HEADS
            if (act) {
                float* outA = out + ((bbase + k) * T_DIM + t) * 18;
                outA[j] = o0; outA[8 + j] = o1;
                if (j < 2) outA[16 + j] = o2;
                else if (j == 2)
                    out[(size_t)18 * B_DIM * T_DIM + (bbase + k) * T_DIM + t] = o2;
            }
        }
        if (fd < SEGLEN) {
#pragma unroll
            for (int m = 0; m < 8; ++m)
                h[m] = carryH[((size_t)s * T_DIM + t) * 8 + m];
            c = carryC[((size_t)s * T_DIM + t) * 8 + j];
        }
    }
}

// ---------------------------------------------------------------------------
extern "C" void kernel_launch(void* const* d_in, const int* in_sizes, int n_in,
                              void* d_out, int out_size, void* d_ws, size_t ws_size,
                              hipStream_t stream) {
    (void)in_sizes; (void)n_in; (void)out_size; (void)ws_size;
    const float* states = (const float*)d_in[0];
    const int*   dones  = (const int*)d_in[1];
    const float* hx     = (const float*)d_in[2];
    const float* W1     = (const float*)d_in[3];
    const float* b1     = (const float*)d_in[4];
    const float* W2     = (const float*)d_in[5];
    const float* b2     = (const float*)d_in[6];
    const float* Wih    = (const float*)d_in[7];
    const float* bih    = (const float*)d_in[8];
    const float* Whh    = (const float*)d_in[9];
    const float* bhh    = (const float*)d_in[10];
    const float* Wa     = (const float*)d_in[11];
    const float* ba     = (const float*)d_in[12];
    const float* Wv     = (const float*)d_in[13];
    const float* bv     = (const float*)d_in[14];
    float* out = (float*)d_out;

    float* x2t     = (float*)d_ws;                               // 32 MiB
    int*   dones_t = (int*)((char*)d_ws + (32u << 20));          // 4 MiB
    float* carryH  = (float*)((char*)d_ws + (36u << 20));        // 1 MiB
    float* carryC  = (float*)((char*)d_ws + (37u << 20));        // 1 MiB
    int*   fdbuf   = (int*)((char*)d_ws + (38u << 20));          // 128 KiB

    mlp_kernel<<<(B_DIM * T_DIM) / 64, 256, 0, stream>>>(states, dones, W1, b1, W2, b2,
                                                         x2t, dones_t);
    pass1_kernel<<<NSEG * 512, 64, 0, stream>>>(x2t, dones_t, hx,
                                                Wih, bih, Whh, bhh, Wa, ba, Wv, bv,
                                                out, carryH, carryC, fdbuf);
    pass2_kernel<<<512, 64, 0, stream>>>(x2t, Wih, bih, Whh, bhh, Wa, ba, Wv, bv,
                                         out, carryH, carryC, fdbuf);
}